// Round 1
// baseline (10665.575 us; speedup 1.0000x reference)
//
#include <hip/hip_runtime.h>
#include <hip/hip_bf16.h>
#include <stdint.h>

#define B_ 64
#define S_ 512
#define I_ 512
#define H_ 1024

typedef __attribute__((ext_vector_type(8))) __bf16 bf16x8;
typedef __attribute__((ext_vector_type(4))) float f32x4;

__device__ __forceinline__ unsigned short f2bf(float f) {
    unsigned u = __float_as_uint(f);
    u += 0x7FFFu + ((u >> 16) & 1u);   // RNE
    return (unsigned short)(u >> 16);
}

__device__ __forceinline__ bf16x8 ld8(const unsigned short* p) {
    return *(const bf16x8*)p;
}

// device-scope (cross-XCD coherent) 16B load as 2x8B atomic loads
__device__ __forceinline__ bf16x8 ld8_agent(const unsigned short* p) {
    union { unsigned long long u[2]; bf16x8 v; } cv;
    cv.u[0] = __hip_atomic_load((const unsigned long long*)p,       __ATOMIC_RELAXED, __HIP_MEMORY_SCOPE_AGENT);
    cv.u[1] = __hip_atomic_load((const unsigned long long*)(p + 4), __ATOMIC_RELAXED, __HIP_MEMORY_SCOPE_AGENT);
    return cv.v;
}

// ---------- prep: convert x and W_ih to bf16 ----------
__global__ __launch_bounds__(256) void gru_prep(const float* __restrict__ x,
                                                const float* __restrict__ wih,
                                                unsigned short* __restrict__ xbf,
                                                unsigned short* __restrict__ wbf) {
    const int NX = (B_ * S_ * I_) / 4;   // 4194304 float4
    const int NW = (3 * H_ * I_) / 4;    // 393216 float4
    int stride = gridDim.x * blockDim.x;
    for (int i = blockIdx.x * blockDim.x + threadIdx.x; i < NX + NW; i += stride) {
        float4 v = (i < NX) ? ((const float4*)x)[i] : ((const float4*)wih)[i - NX];
        ushort4 o;
        o.x = f2bf(v.x); o.y = f2bf(v.y); o.z = f2bf(v.z); o.w = f2bf(v.w);
        if (i < NX) ((ushort4*)xbf)[i] = o; else ((ushort4*)wbf)[i - NX] = o;
    }
}

// ---------- persistent scan ----------
// 128 blocks, block g owns h columns [8g, 8g+8). 4 waves, wave w = batches [16w,16w+16).
// Tiles (16x16x32 bf16 mfma, D: col=lane&15 -> weight-row, row=(lane>>4)*4+reg -> batch):
//   arz: cols 0-7 = r, 8-15 = z (x- and h-matmul fused + both biases)
//   axn: cols 0-7 = xn (x-matmul + b_ih), rows 8-15 duplicated
//   ahn: cols 0-7 = hn (h-matmul + b_hh), rows 8-15 duplicated
__global__ __launch_bounds__(256, 1) void gru_scan(
    const unsigned short* __restrict__ xbf,
    const unsigned short* __restrict__ wihbf,
    const float* __restrict__ mask,
    const float* __restrict__ init_h,
    const float* __restrict__ dmask,
    const float* __restrict__ Whh,
    const float* __restrict__ bih,
    const float* __restrict__ bhh,
    float* __restrict__ out,
    float* __restrict__ out_last,
    unsigned* __restrict__ flags,
    unsigned short* __restrict__ hbuf)   // 2 buffers of 64*1024 bf16
{
    // rows 0-7: W_hh r-rows, 8-15: z-rows, 16-23: n-rows. stride 1032 (pad 8) -> 2-way LDS conflicts only.
    __shared__ unsigned short wlds[24 * 1032];

    const int g   = blockIdx.x;
    const int tid = threadIdx.x;
    const int w   = tid >> 6;        // wave = M-tile
    const int l   = tid & 63;
    const int q   = l >> 4;          // k-quad
    const int c   = l & 15;          // n-col (weight row) / m-row for A
    const int c8  = c & 7;

    // stage W_hh slice -> LDS bf16
    for (int idx = tid; idx < 24 * 1024; idx += 256) {
        int row = idx >> 10, col = idx & 1023;
        int sr = (row < 8) ? (g * 8 + row)
               : (row < 16) ? (H_ + g * 8 + row - 8)
                            : (2 * H_ + g * 8 + row - 16);
        wlds[row * 1032 + col] = f2bf(Whh[(size_t)sr * H_ + col]);
    }

    const int jd = g * 8 + c8;
    const int wr_rz = (c < 8) ? (g * 8 + c) : (H_ + g * 8 + (c - 8));
    const int wr_xn = 2 * H_ + jd;
    const float brz_b = (c < 8) ? (bih[g * 8 + c] + bhh[g * 8 + c])
                                : (bih[H_ + g * 8 + c - 8] + bhh[H_ + g * 8 + c - 8]);
    const float bxn_b = bih[2 * H_ + jd];
    const float bhn_b = bhh[2 * H_ + jd];

    const int batch_A = w * 16 + c;  // A-frag batch (m = lane&15)

    // per-(reg) state, C-layout batches
    float dm[4], hd[4], mc[4];
    int batch_C[4];
    #pragma unroll
    for (int r = 0; r < 4; ++r) {
        batch_C[r] = w * 16 + q * 4 + r;
        dm[r] = dmask[batch_C[r] * H_ + jd];
        float m1 = mask[batch_C[r] * S_ + 0];
        float h0 = init_h[batch_C[r] * H_ + jd];
        hd[r] = h0 * (dm[r] * m1 + 1.0f - m1);   // pre-dropped h for step 1
        mc[r] = m1;
        if (c < 8)
            __hip_atomic_store(&hbuf[65536 + batch_C[r] * H_ + jd], f2bf(hd[r]),
                               __ATOMIC_RELAXED, __HIP_MEMORY_SCOPE_AGENT);
    }
    __builtin_amdgcn_fence(__ATOMIC_RELEASE, "agent");
    __syncthreads();   // covers LDS staging + all threads' h stores fenced
    if (tid == 0)
        __hip_atomic_store(&flags[g], 1u, __ATOMIC_RELAXED, __HIP_MEMORY_SCOPE_AGENT);

    const int off_rz = c * 1032 + q * 8;
    const int off_hn = (16 + c8) * 1032 + q * 8;

    for (int t = 1; t <= S_; ++t) {
        const int s = t - 1;
        f32x4 arz, axn, ahn;
        #pragma unroll
        for (int r = 0; r < 4; ++r) { arz[r] = brz_b; axn[r] = bxn_b; ahn[r] = bhn_b; }

        float mn[4];
        if (t < S_) {
            #pragma unroll
            for (int r = 0; r < 4; ++r) mn[r] = mask[batch_C[r] * S_ + t];
        }

        // ---- x phase (h-independent: runs while other blocks finish step t-1) ----
        {
            const unsigned short* xp  = xbf + (size_t)batch_A * (S_ * I_) + s * I_ + q * 8;
            const unsigned short* wrz = wihbf + (size_t)wr_rz * I_ + q * 8;
            const unsigned short* wxn = wihbf + (size_t)wr_xn * I_ + q * 8;
            #pragma unroll 4
            for (int ki = 0; ki < 16; ++ki) {
                bf16x8 a  = ld8(xp  + ki * 32);
                bf16x8 b0 = ld8(wrz + ki * 32);
                bf16x8 b1 = ld8(wxn + ki * 32);
                arz = __builtin_amdgcn_mfma_f32_16x16x32_bf16(a, b0, arz, 0, 0, 0);
                axn = __builtin_amdgcn_mfma_f32_16x16x32_bf16(a, b1, axn, 0, 0, 0);
            }
        }

        // ---- wait until every block posted h for step t ----
        if (tid < 64) {
            const unsigned long long* f2 = (const unsigned long long*)flags;
            for (;;) {
                unsigned long long v = __hip_atomic_load(&f2[tid], __ATOMIC_RELAXED,
                                                         __HIP_MEMORY_SCOPE_AGENT);
                bool ok = ((unsigned)v >= (unsigned)t) && ((unsigned)(v >> 32) >= (unsigned)t);
                if (__all(ok)) break;
                __builtin_amdgcn_s_sleep(1);
            }
        }
        __syncthreads();

        // ---- h phase ----
        {
            const unsigned short* hp = hbuf + (t & 1) * 65536 + batch_A * H_ + q * 8;
            #pragma unroll 8
            for (int ki = 0; ki < 32; ++ki) {
                bf16x8 a  = ld8_agent(hp + ki * 32);
                bf16x8 b0 = *(const bf16x8*)&wlds[off_rz + ki * 32];
                bf16x8 b1 = *(const bf16x8*)&wlds[off_hn + ki * 32];
                arz = __builtin_amdgcn_mfma_f32_16x16x32_bf16(a, b0, arz, 0, 0, 0);
                ahn = __builtin_amdgcn_mfma_f32_16x16x32_bf16(a, b1, ahn, 0, 0, 0);
            }
        }

        // ---- gates + state update ----
        #pragma unroll
        for (int r = 0; r < 4; ++r) {
            float zpre = __shfl(arz[r], (l & 48) | ((c + 8) & 15), 64); // z lives 8 cols over
            float rr = __builtin_amdgcn_rcpf(1.0f + __expf(-arz[r]));
            float zz = __builtin_amdgcn_rcpf(1.0f + __expf(-zpre));
            float narg = axn[r] + rr * ahn[r];
            float E = __expf(-2.0f * fabsf(narg));
            float nn = copysignf((1.0f - E) * __builtin_amdgcn_rcpf(1.0f + E), narg);
            float m = mc[r];
            float curr = (1.0f - zz) * nn + zz * hd[r];
            float hnew = m * curr + (1.0f - m) * hd[r];
            if (c < 8)
                out[((size_t)batch_C[r] * S_ + s) * H_ + jd] = hnew;
            if (t < S_) {
                hd[r] = hnew * (dm[r] * mn[r] + 1.0f - mn[r]);  // pre-drop for step t+1
                mc[r] = mn[r];
                if (c < 8)
                    __hip_atomic_store(&hbuf[((t + 1) & 1) * 65536 + batch_C[r] * H_ + jd],
                                       f2bf(hd[r]), __ATOMIC_RELAXED, __HIP_MEMORY_SCOPE_AGENT);
            } else if (c < 8) {
                out_last[batch_C[r] * H_ + jd] = hnew;
            }
        }

        if (t < S_) {
            __builtin_amdgcn_fence(__ATOMIC_RELEASE, "agent"); // drain stores (thread-local)
            __syncthreads();                                    // => whole block drained
            if (tid == 0)
                __hip_atomic_store(&flags[g], (unsigned)(t + 1), __ATOMIC_RELAXED,
                                   __HIP_MEMORY_SCOPE_AGENT);
        }
    }
}

extern "C" void kernel_launch(void* const* d_in, const int* in_sizes, int n_in,
                              void* d_out, int out_size, void* d_ws, size_t ws_size,
                              hipStream_t stream) {
    (void)in_sizes; (void)n_in; (void)out_size; (void)ws_size;
    const float* x     = (const float*)d_in[0];
    const float* mask  = (const float*)d_in[1];
    const float* inith = (const float*)d_in[2];
    const float* dmask = (const float*)d_in[3];
    const float* Wih   = (const float*)d_in[4];
    const float* Whh   = (const float*)d_in[5];
    const float* bih   = (const float*)d_in[6];
    const float* bhh   = (const float*)d_in[7];
    float* out      = (float*)d_out;
    float* out_last = out + (size_t)B_ * S_ * H_;

    char* ws = (char*)d_ws;
    unsigned* flags       = (unsigned*)ws;                         // 4 KB (flags; memset 0)
    unsigned short* hbuf  = (unsigned short*)(ws + 4096);          // 256 KB (2x h_bf)
    unsigned short* xbf   = (unsigned short*)(ws + 4096 + 262144); // 32 MB
    unsigned short* wbf   = xbf + (size_t)B_ * S_ * I_;            // 3 MB

    hipMemsetAsync(ws, 0, 4096, stream);
    gru_prep<<<2048, 256, 0, stream>>>(x, Wih, xbf, wbf);
    gru_scan<<<128, 256, 0, stream>>>(xbf, wbf, mask, inith, dmask, Whh, bih, bhh,
                                      out, out_last, flags, hbuf);
}

// Round 3
// 7182.665 us; speedup vs baseline: 1.4849x; 1.4849x over previous
//
#include <hip/hip_runtime.h>
#include <hip/hip_bf16.h>
#include <stdint.h>

#define B_ 64
#define S_ 512
#define I_ 512
#define H_ 1024

typedef __attribute__((ext_vector_type(8))) __bf16 bf16x8;
typedef __attribute__((ext_vector_type(4))) float f32x4;

__device__ __forceinline__ unsigned short f2bf(float f) {
    unsigned u = __float_as_uint(f);
    u += 0x7FFFu + ((u >> 16) & 1u);   // RNE
    return (unsigned short)(u >> 16);
}

__device__ __forceinline__ bf16x8 ld8(const unsigned short* p) {
    return *(const bf16x8*)p;
}

// ---------- prep: convert x and W_ih to bf16 ----------
__global__ __launch_bounds__(256) void gru_prep(const float* __restrict__ x,
                                                const float* __restrict__ wih,
                                                unsigned short* __restrict__ xbf,
                                                unsigned short* __restrict__ wbf) {
    const int NX = (B_ * S_ * I_) / 4;   // 4194304 float4
    const int NW = (3 * H_ * I_) / 4;    // 393216 float4
    int stride = gridDim.x * blockDim.x;
    for (int i = blockIdx.x * blockDim.x + threadIdx.x; i < NX + NW; i += stride) {
        float4 v = (i < NX) ? ((const float4*)x)[i] : ((const float4*)wih)[i - NX];
        ushort4 o;
        o.x = f2bf(v.x); o.y = f2bf(v.y); o.z = f2bf(v.z); o.w = f2bf(v.w);
        if (i < NX) ((ushort4*)xbf)[i] = o; else ((ushort4*)wbf)[i - NX] = o;
    }
}

// ---------- persistent scan ----------
// 128 blocks, block g owns h columns [8g, 8g+8). 4 waves, wave w = batches [16w,16w+16).
//
// h exchange layout (block-contiguous to avoid cross-XCD partial-line writebacks):
//   element (j = 8*gj + cj, batch) lives at hbuf[buf*65536 + gj*512 + batch*8 + cj].
//   Block g writes exactly bytes [g*1024, g*1024+1024) of each buffer: 8 whole
//   128B lines, single-writer -> L2 writeback cannot corrupt other blocks' data.
//
// Sync fabric: per-step counter cnt[t]. Producer: __syncthreads (drains the
// block's h stores to L2, vmcnt(0)) then ONE release-scope atomicAdd by tid0
// (emits buffer_wbl2: whole-L2 writeback -> mall, covering all threads' stores,
// then bumps the counter at the mall). Consumer: tid0 polls one dword relaxed,
// then fence(acquire, agent) (buffer_inv: invalidates this CU's L1 + XCD's L2
// clean lines) INSIDE tid0's branch, then __syncthreads -> all threads' plain
// cached h loads re-fetch fresh lines from the mall.
__global__ __launch_bounds__(256, 1) void gru_scan(
    const unsigned short* __restrict__ xbf,
    const unsigned short* __restrict__ wihbf,
    const float* __restrict__ mask,
    const float* __restrict__ init_h,
    const float* __restrict__ dmask,
    const float* __restrict__ Whh,
    const float* __restrict__ bih,
    const float* __restrict__ bhh,
    float* __restrict__ out,
    float* __restrict__ out_last,
    unsigned* __restrict__ cnt,          // [S_+1] step counters, zeroed at launch
    unsigned short* __restrict__ hbuf)   // 2 buffers of 64*1024 bf16, block-contiguous
{
    // rows 0-7: W_hh r-rows, 8-15: z-rows, 16-23: n-rows. stride 1032 (pad 8).
    __shared__ unsigned short wlds[24 * 1032];

    const int g   = blockIdx.x;
    const int tid = threadIdx.x;
    const int w   = tid >> 6;        // wave = M-tile (batches)
    const int l   = tid & 63;
    const int q   = l >> 4;          // k-quad
    const int c   = l & 15;          // n-col (weight row) / m-row for A
    const int c8  = c & 7;

    // stage W_hh slice -> LDS bf16
    for (int idx = tid; idx < 24 * 1024; idx += 256) {
        int row = idx >> 10, col = idx & 1023;
        int sr = (row < 8) ? (g * 8 + row)
               : (row < 16) ? (H_ + g * 8 + row - 8)
                            : (2 * H_ + g * 8 + row - 16);
        wlds[row * 1032 + col] = f2bf(Whh[(size_t)sr * H_ + col]);
    }

    const int jd = g * 8 + c8;
    const int wr_rz = (c < 8) ? (g * 8 + c) : (H_ + g * 8 + (c - 8));
    const int wr_xn = 2 * H_ + jd;
    const float brz_b = (c < 8) ? (bih[g * 8 + c] + bhh[g * 8 + c])
                                : (bih[H_ + g * 8 + c - 8] + bhh[H_ + g * 8 + c - 8]);
    const float bxn_b = bih[2 * H_ + jd];
    const float bhn_b = bhh[2 * H_ + jd];

    const int batch_A = w * 16 + c;  // A-frag batch (m = lane&15)

    // per-(reg) state, C-layout batches
    float dm[4], hd[4], mc[4];
    int batch_C[4];
    #pragma unroll
    for (int r = 0; r < 4; ++r) {
        batch_C[r] = w * 16 + q * 4 + r;
        dm[r] = dmask[batch_C[r] * H_ + jd];
        float m1 = mask[batch_C[r] * S_ + 0];
        float h0 = init_h[batch_C[r] * H_ + jd];
        hd[r] = h0 * (dm[r] * m1 + 1.0f - m1);   // pre-dropped h for step 1
        mc[r] = m1;
        if (c < 8)
            hbuf[65536 + g * 512 + batch_C[r] * 8 + c8] = f2bf(hd[r]);   // buffer 1
    }
    __syncthreads();   // LDS staging done + all threads' h stores drained to L2
    if (tid == 0)
        __hip_atomic_fetch_add(&cnt[1], 1u, __ATOMIC_RELEASE, __HIP_MEMORY_SCOPE_AGENT);

    const int off_rz = c * 1032 + q * 8;
    const int off_hn = (16 + c8) * 1032 + q * 8;

    for (int t = 1; t <= S_; ++t) {
        const int s = t - 1;
        f32x4 arz, axn, ahn;
        #pragma unroll
        for (int r = 0; r < 4; ++r) { arz[r] = brz_b; axn[r] = bxn_b; ahn[r] = bhn_b; }

        float mn[4];
        if (t < S_) {
            #pragma unroll
            for (int r = 0; r < 4; ++r) mn[r] = mask[batch_C[r] * S_ + t];
        }

        // ---- x phase (h-independent: overlaps other blocks finishing step t-1) ----
        {
            const unsigned short* xp  = xbf + (size_t)batch_A * (S_ * I_) + s * I_ + q * 8;
            const unsigned short* wrz = wihbf + (size_t)wr_rz * I_ + q * 8;
            const unsigned short* wxn = wihbf + (size_t)wr_xn * I_ + q * 8;
            #pragma unroll 4
            for (int ki = 0; ki < 16; ++ki) {
                bf16x8 a  = ld8(xp  + ki * 32);
                bf16x8 b0 = ld8(wrz + ki * 32);
                bf16x8 b1 = ld8(wxn + ki * 32);
                arz = __builtin_amdgcn_mfma_f32_16x16x32_bf16(a, b0, arz, 0, 0, 0);
                axn = __builtin_amdgcn_mfma_f32_16x16x32_bf16(a, b1, axn, 0, 0, 0);
            }
        }

        // ---- wait until every block posted h for step t ----
        if (tid == 0) {
            int spins = 0;
            while (__hip_atomic_load(&cnt[t], __ATOMIC_RELAXED,
                                     __HIP_MEMORY_SCOPE_AGENT) < 128u) {
                __builtin_amdgcn_s_sleep(1);
                if (++spins > 40000) break;   // safety valve: deadlock -> wrong answer, not hang
            }
            // acquire in the thread that observed the flag; barrier propagates
            __builtin_amdgcn_fence(__ATOMIC_ACQUIRE, "agent");
        }
        __syncthreads();

        // ---- h phase (plain cached 16B loads, block-contiguous layout) ----
        {
            const unsigned short* hp = hbuf + (t & 1) * 65536 + q * 512 + batch_A * 8;
            #pragma unroll 8
            for (int ki = 0; ki < 32; ++ki) {
                bf16x8 a  = ld8(hp + ki * 2048);           // k-group stride: 4*512 elems
                bf16x8 b0 = *(const bf16x8*)&wlds[off_rz + ki * 32];
                bf16x8 b1 = *(const bf16x8*)&wlds[off_hn + ki * 32];
                arz = __builtin_amdgcn_mfma_f32_16x16x32_bf16(a, b0, arz, 0, 0, 0);
                ahn = __builtin_amdgcn_mfma_f32_16x16x32_bf16(a, b1, ahn, 0, 0, 0);
            }
        }

        // ---- gates + state update ----
        #pragma unroll
        for (int r = 0; r < 4; ++r) {
            float zpre = __shfl(arz[r], (l & 48) | ((c + 8) & 15), 64); // z lives 8 cols over
            float rr = __builtin_amdgcn_rcpf(1.0f + __expf(-arz[r]));
            float zz = __builtin_amdgcn_rcpf(1.0f + __expf(-zpre));
            float narg = axn[r] + rr * ahn[r];
            float E = __expf(-2.0f * fabsf(narg));
            float nn = copysignf((1.0f - E) * __builtin_amdgcn_rcpf(1.0f + E), narg);
            float m = mc[r];
            float curr = (1.0f - zz) * nn + zz * hd[r];
            float hnew = m * curr + (1.0f - m) * hd[r];
            if (c < 8)
                out[((size_t)batch_C[r] * S_ + s) * H_ + jd] = hnew;
            if (t < S_) {
                hd[r] = hnew * (dm[r] * mn[r] + 1.0f - mn[r]);  // pre-drop for step t+1
                mc[r] = mn[r];
                if (c < 8)
                    hbuf[((t + 1) & 1) * 65536 + g * 512 + batch_C[r] * 8 + c8] = f2bf(hd[r]);
            } else if (c < 8) {
                out_last[batch_C[r] * H_ + jd] = hnew;
            }
        }

        if (t < S_) {
            __syncthreads();   // drains all threads' h stores to L2 (vmcnt(0) pre-barrier)
            if (tid == 0)      // release: buffer_wbl2 (L2->mall) then bump counter at mall
                __hip_atomic_fetch_add(&cnt[t + 1], 1u, __ATOMIC_RELEASE,
                                       __HIP_MEMORY_SCOPE_AGENT);
        }
    }
}

extern "C" void kernel_launch(void* const* d_in, const int* in_sizes, int n_in,
                              void* d_out, int out_size, void* d_ws, size_t ws_size,
                              hipStream_t stream) {
    (void)in_sizes; (void)n_in; (void)out_size; (void)ws_size;
    const float* x     = (const float*)d_in[0];
    const float* mask  = (const float*)d_in[1];
    const float* inith = (const float*)d_in[2];
    const float* dmask = (const float*)d_in[3];
    const float* Wih   = (const float*)d_in[4];
    const float* Whh   = (const float*)d_in[5];
    const float* bih   = (const float*)d_in[6];
    const float* bhh   = (const float*)d_in[7];
    float* out      = (float*)d_out;
    float* out_last = out + (size_t)B_ * S_ * H_;

    char* ws = (char*)d_ws;
    unsigned* cnt         = (unsigned*)ws;                         // 8 KB (step counters)
    unsigned short* hbuf  = (unsigned short*)(ws + 8192);          // 256 KB (2x h_bf)
    unsigned short* xbf   = (unsigned short*)(ws + 8192 + 262144); // 32 MB
    unsigned short* wbf   = xbf + (size_t)B_ * S_ * I_;            // 3 MB

    hipMemsetAsync(ws, 0, 8192, stream);
    gru_prep<<<2048, 256, 0, stream>>>(x, Wih, xbf, wbf);
    gru_scan<<<128, 256, 0, stream>>>(xbf, wbf, mask, inith, dmask, Whh, bih, bhh,
                                      out, out_last, cnt, hbuf);
}